// Round 2
// baseline (860.441 us; speedup 1.0000x reference)
//
#include <hip/hip_runtime.h>

#define N_NODES 100000
#define N_EDGES 1600000
#define F_NODE  32
#define F_GLOB  16
#define HDIM    64
#define OUTDIM  64
#define GROWS   16   // rows per block in dense kernels

// ---------- CSR build ----------

__global__ void k_hist(const int* __restrict__ dst, int* __restrict__ cnt) {
    int e = blockIdx.x * blockDim.x + threadIdx.x;
    if (e < N_EDGES) atomicAdd(&cnt[dst[e]], 1);
}

__global__ void k_dis(const int* __restrict__ cnt, float* __restrict__ dis) {
    int v = blockIdx.x * blockDim.x + threadIdx.x;
    if (v < N_NODES) dis[v] = rsqrtf((float)(cnt[v] + 1));  // +1 self-loop
}

__global__ void k_scan1(const int* __restrict__ cnt, int* __restrict__ rowptr,
                        int* __restrict__ bsum) {
    __shared__ int lds[256];
    int t = threadIdx.x;
    int i = blockIdx.x * 256 + t;
    int v = (i < N_NODES) ? cnt[i] : 0;
    int x = v;
    lds[t] = x;
    __syncthreads();
    for (int ofs = 1; ofs < 256; ofs <<= 1) {
        int y = (t >= ofs) ? lds[t - ofs] : 0;
        __syncthreads();
        x += y;
        lds[t] = x;
        __syncthreads();
    }
    if (i < N_NODES) rowptr[i] = x - v;        // block-local exclusive
    if (t == 255)    bsum[blockIdx.x] = x;     // block total
}

__global__ void k_scan2(int* __restrict__ bsum, int nb, int* __restrict__ rowptr) {
    __shared__ int lds[512];
    int t = threadIdx.x;
    int v = (t < nb) ? bsum[t] : 0;
    int x = v;
    lds[t] = x;
    __syncthreads();
    for (int ofs = 1; ofs < 512; ofs <<= 1) {
        int y = (t >= ofs) ? lds[t - ofs] : 0;
        __syncthreads();
        x += y;
        lds[t] = x;
        __syncthreads();
    }
    if (t < nb) bsum[t] = x - v;               // exclusive over block totals
    if (t == 0) rowptr[N_NODES] = N_EDGES;
}

__global__ void k_scan3(int* __restrict__ rowptr, const int* __restrict__ bsum) {
    int i = blockIdx.x * 256 + threadIdx.x;
    if (i < N_NODES) rowptr[i] += bsum[blockIdx.x];
}

// only col is scattered now — norm weight folded into dense kernels via dis
__global__ void k_scatter(const int* __restrict__ src, const int* __restrict__ dst,
                          const int* __restrict__ rowptr, int* __restrict__ fill,
                          int* __restrict__ col) {
    int e = blockIdx.x * blockDim.x + threadIdx.x;
    if (e < N_EDGES) {
        int d = dst[e];
        int pos = rowptr[d] + atomicAdd(&fill[d], 1);
        col[pos] = src[e];
    }
}

// ---------- dense kernels ----------

// layer 0 fused: hw' = dis * ((x @ w_node + b_node) @ w_c0)
__global__ void __launch_bounds__(256)
k_embed_gemm(const float* __restrict__ x, const float* __restrict__ wn,
             const float* __restrict__ bn, const float* __restrict__ wc,
             const float* __restrict__ dis, float* __restrict__ hw) {
    __shared__ float wnl[F_NODE * HDIM];   // 8 KB
    __shared__ float wcl[HDIM * HDIM];     // 16 KB
    __shared__ float xl[GROWS * F_NODE];   // 2 KB
    __shared__ float tl[GROWS * HDIM];     // 4 KB
    int t = threadIdx.x;
    for (int i = t; i < F_NODE * HDIM; i += 256) wnl[i] = wn[i];
    for (int i = t; i < HDIM * HDIM; i += 256)   wcl[i] = wc[i];
    int row0 = blockIdx.x * GROWS;
    for (int i = t; i < GROWS * F_NODE; i += 256) {
        int r = i >> 5, k = i & 31;
        int rr = row0 + r;
        xl[i] = (rr < N_NODES) ? x[(size_t)rr * F_NODE + k] : 0.f;
    }
    __syncthreads();
    int c = t & 63, rbase = t >> 6;
    float bc = bn[c];
    #pragma unroll
    for (int j = 0; j < 4; ++j) {
        int r = rbase + 4 * j;
        float acc = bc;
        #pragma unroll
        for (int k = 0; k < F_NODE; ++k) acc += xl[r * F_NODE + k] * wnl[k * HDIM + c];
        tl[r * HDIM + c] = acc;
    }
    __syncthreads();
    float acc[4] = {0.f, 0.f, 0.f, 0.f};
    for (int k = 0; k < HDIM; ++k) {
        float wv = wcl[k * HDIM + c];
        #pragma unroll
        for (int j = 0; j < 4; ++j) acc[j] += tl[(rbase + 4 * j) * HDIM + k] * wv;
    }
    #pragma unroll
    for (int j = 0; j < 4; ++j) {
        int row = row0 + rbase + 4 * j;
        if (row < N_NODES)
            hw[(size_t)row * HDIM + c] = dis[row] * acc[j];
    }
}

// hw' = dis * (h @ w), 16 rows per block
__global__ void __launch_bounds__(256)
k_gemm16(const float* __restrict__ h, const float* __restrict__ w,
         const float* __restrict__ dis, float* __restrict__ hw) {
    __shared__ float wl[HDIM * HDIM];     // 16 KB
    __shared__ float xl[GROWS * HDIM];    // 4 KB
    int t = threadIdx.x;
    for (int i = t; i < HDIM * HDIM; i += 256) wl[i] = w[i];
    int row0 = blockIdx.x * GROWS;
    for (int i = t; i < GROWS * HDIM; i += 256) {
        int r = i >> 6, k = i & 63;
        int rr = row0 + r;
        xl[i] = (rr < N_NODES) ? h[(size_t)rr * HDIM + k] : 0.f;
    }
    __syncthreads();
    int c = t & 63, rbase = t >> 6;
    float acc[4] = {0.f, 0.f, 0.f, 0.f};
    for (int k = 0; k < HDIM; ++k) {
        float wv = wl[k * HDIM + c];
        #pragma unroll
        for (int j = 0; j < 4; ++j) acc[j] += xl[(rbase + 4 * j) * HDIM + k] * wv;
    }
    #pragma unroll
    for (int j = 0; j < 4; ++j) {
        int row = row0 + rbase + 4 * j;
        if (row < N_NODES)
            hw[(size_t)row * HDIM + c] = dis[row] * acc[j];
    }
}

// pull aggregation: out[v] = relu(b + dis[v] * (hw'[v] + sum_{c in N(v)} hw'[c]))
__global__ void __launch_bounds__(256)
k_pull(const float* __restrict__ hw, const int* __restrict__ rowptr,
       const int* __restrict__ col, const float* __restrict__ dis,
       const float* __restrict__ b, float* __restrict__ hout) {
    int wid = threadIdx.x >> 6, lane = threadIdx.x & 63;
    int v = blockIdx.x * 4 + wid;
    if (v >= N_NODES) return;
    float acc = hw[(size_t)v * HDIM + lane];   // self-loop term
    int s0 = rowptr[v], s1 = rowptr[v + 1];
    for (int base = s0; base < s1; base += 64) {
        int m = s1 - base; if (m > 64) m = 64;
        int c = 0;
        if (lane < m) c = col[base + lane];
        int i = 0;
        for (; i + 4 <= m; i += 4) {
            int c0 = __shfl(c, i), c1 = __shfl(c, i + 1);
            int c2 = __shfl(c, i + 2), c3 = __shfl(c, i + 3);
            float a0 = hw[(size_t)c0 * HDIM + lane];
            float a1 = hw[(size_t)c1 * HDIM + lane];
            float a2 = hw[(size_t)c2 * HDIM + lane];
            float a3 = hw[(size_t)c3 * HDIM + lane];
            acc += (a0 + a1) + (a2 + a3);
        }
        for (; i < m; ++i) {
            int cs = __shfl(c, i);
            acc += hw[(size_t)cs * HDIM + lane];
        }
    }
    hout[(size_t)v * HDIM + lane] = fmaxf(b[lane] + dis[v] * acc, 0.f);
}

// ---------- readout ----------

__global__ void k_mean(const float* __restrict__ h, float* __restrict__ partial) {
    __shared__ float lds[256];
    int t = threadIdx.x;
    int f = t & 63, g = t >> 6;
    float acc = 0.f;
    for (int v = blockIdx.x * 4 + g; v < N_NODES; v += gridDim.x * 4)
        acc += h[(size_t)v * HDIM + f];
    lds[t] = acc;
    __syncthreads();
    if (t < 64)
        partial[blockIdx.x * 64 + t] = lds[t] + lds[t + 64] + lds[t + 128] + lds[t + 192];
}

__global__ void k_final(const float* __restrict__ partial, int nparts,
                        const float* __restrict__ gfeat,
                        const float* __restrict__ wg, const float* __restrict__ bg,
                        const float* __restrict__ w1, const float* __restrict__ b1,
                        const float* __restrict__ w2, const float* __restrict__ b2,
                        float* __restrict__ out) {
    __shared__ float xc[2 * HDIM];
    __shared__ float hid[HDIM];
    int t = threadIdx.x;   // 64 threads
    float s = 0.f;
    for (int p = 0; p < nparts; ++p) s += partial[p * 64 + t];
    xc[t] = s / (float)N_NODES;                       // x_graph
    float gacc = bg[t];
    for (int k = 0; k < F_GLOB; ++k) gacc += gfeat[k] * wg[k * HDIM + t];
    xc[HDIM + t] = fmaxf(gacc, 0.f);                  // x_global
    __syncthreads();
    float hacc = b1[t];
    for (int k = 0; k < 2 * HDIM; ++k) hacc += xc[k] * w1[k * HDIM + t];
    hid[t] = fmaxf(hacc, 0.f);
    __syncthreads();
    float oacc = b2[t];
    for (int k = 0; k < HDIM; ++k) oacc += hid[k] * w2[k * OUTDIM + t];
    out[t] = oacc;
}

// ---------- launch ----------

extern "C" void kernel_launch(void* const* d_in, const int* in_sizes, int n_in,
                              void* d_out, int out_size, void* d_ws, size_t ws_size,
                              hipStream_t stream) {
    const float* x      = (const float*)d_in[0];
    const int*   eidx   = (const int*)d_in[1];
    const float* gfeat  = (const float*)d_in[2];
    const float* w_node = (const float*)d_in[3];
    const float* b_node = (const float*)d_in[4];
    const float* w_glob = (const float*)d_in[5];
    const float* b_glob = (const float*)d_in[6];
    const float* w_c[3] = {(const float*)d_in[7], (const float*)d_in[9], (const float*)d_in[11]};
    const float* b_c[3] = {(const float*)d_in[8], (const float*)d_in[10], (const float*)d_in[12]};
    const float* w_fc1  = (const float*)d_in[13];
    const float* b_fc1  = (const float*)d_in[14];
    const float* w_fc2  = (const float*)d_in[15];
    const float* b_fc2  = (const float*)d_in[16];
    float* out = (float*)d_out;

    const int* srcp = eidx;
    const int* dstp = eidx + N_EDGES;

    char* ws = (char*)d_ws;
    size_t off = 0;
    auto alloc = [&](size_t bytes) -> void* {
        void* p = ws + off;
        off = (off + bytes + 255) & ~(size_t)255;
        return p;
    };
    int*   cnt     = (int*)  alloc((size_t)N_NODES * 4);
    int*   rowptr  = (int*)  alloc((size_t)(N_NODES + 1) * 4);
    int*   fill    = (int*)  alloc((size_t)N_NODES * 4);
    int*   bsum    = (int*)  alloc(512 * 4);
    float* dis     = (float*)alloc((size_t)N_NODES * 4);
    int*   col     = (int*)  alloc((size_t)N_EDGES * 4);
    float* hbuf    = (float*)alloc((size_t)N_NODES * HDIM * 4);
    float* hwbuf   = (float*)alloc((size_t)N_NODES * HDIM * 4);
    float* partial = (float*)alloc(256 * 64 * 4);

    hipMemsetAsync(cnt,  0, (size_t)N_NODES * 4, stream);
    hipMemsetAsync(fill, 0, (size_t)N_NODES * 4, stream);

    int eb = (N_EDGES + 255) / 256;
    int nb = (N_NODES + 255) / 256;   // 391 (< 512, fits k_scan2)
    k_hist   <<<eb, 256, 0, stream>>>(dstp, cnt);
    k_dis    <<<nb, 256, 0, stream>>>(cnt, dis);
    k_scan1  <<<nb, 256, 0, stream>>>(cnt, rowptr, bsum);
    k_scan2  <<<1, 512, 0, stream>>>(bsum, nb, rowptr);
    k_scan3  <<<nb, 256, 0, stream>>>(rowptr, bsum);
    k_scatter<<<eb, 256, 0, stream>>>(srcp, dstp, rowptr, fill, col);

    int gb = (N_NODES + GROWS - 1) / GROWS;   // 6250
    int pb = (N_NODES + 3) / 4;               // 25000, 1 node per wave

    // layer 0 (embed fused in)
    k_embed_gemm<<<gb, 256, 0, stream>>>(x, w_node, b_node, w_c[0], dis, hwbuf);
    k_pull      <<<pb, 256, 0, stream>>>(hwbuf, rowptr, col, dis, b_c[0], hbuf);
    // layers 1,2
    for (int l = 1; l < 3; ++l) {
        k_gemm16<<<gb, 256, 0, stream>>>(hbuf, w_c[l], dis, hwbuf);
        k_pull  <<<pb, 256, 0, stream>>>(hwbuf, rowptr, col, dis, b_c[l], hbuf);
    }
    k_mean <<<256, 256, 0, stream>>>(hbuf, partial);
    k_final<<<1, 64, 0, stream>>>(partial, 256, gfeat, w_glob, b_glob,
                                  w_fc1, b_fc1, w_fc2, b_fc2, out);
}

// Round 3
// 635.825 us; speedup vs baseline: 1.3533x; 1.3533x over previous
//
#include <hip/hip_runtime.h>

#define N_NODES 100000
#define N_EDGES 1600000
#define F_NODE  32
#define F_GLOB  16
#define HDIM    64
#define OUTDIM  64
#define GB      2048   // persistent blocks for dense GEMMs

// ---------- CSR build ----------

__global__ void k_hist(const int* __restrict__ dst, int* __restrict__ cnt) {
    int e = blockIdx.x * blockDim.x + threadIdx.x;
    if (e < N_EDGES) atomicAdd(&cnt[dst[e]], 1);
}

// scan1 + dis fused (dis = rsqrt(deg+1), independent elementwise on cnt)
__global__ void k_scan1(const int* __restrict__ cnt, int* __restrict__ rowptr,
                        int* __restrict__ bsum, float* __restrict__ dis) {
    __shared__ int lds[256];
    int t = threadIdx.x;
    int i = blockIdx.x * 256 + t;
    int v = (i < N_NODES) ? cnt[i] : 0;
    if (i < N_NODES) dis[i] = rsqrtf((float)(v + 1));   // +1 self-loop
    int x = v;
    lds[t] = x;
    __syncthreads();
    for (int ofs = 1; ofs < 256; ofs <<= 1) {
        int y = (t >= ofs) ? lds[t - ofs] : 0;
        __syncthreads();
        x += y;
        lds[t] = x;
        __syncthreads();
    }
    if (i < N_NODES) rowptr[i] = x - v;        // block-local exclusive
    if (t == 255)    bsum[blockIdx.x] = x;     // block total
}

__global__ void k_scan2(int* __restrict__ bsum, int nb, int* __restrict__ rowptr) {
    __shared__ int lds[512];
    int t = threadIdx.x;
    int v = (t < nb) ? bsum[t] : 0;
    int x = v;
    lds[t] = x;
    __syncthreads();
    for (int ofs = 1; ofs < 512; ofs <<= 1) {
        int y = (t >= ofs) ? lds[t - ofs] : 0;
        __syncthreads();
        x += y;
        lds[t] = x;
        __syncthreads();
    }
    if (t < nb) bsum[t] = x - v;
    if (t == 0) rowptr[N_NODES] = N_EDGES;
}

__global__ void k_scan3(int* __restrict__ rowptr, const int* __restrict__ bsum) {
    int i = blockIdx.x * 256 + threadIdx.x;
    if (i < N_NODES) rowptr[i] += bsum[blockIdx.x];
}

__global__ void k_scatter(const int* __restrict__ src, const int* __restrict__ dst,
                          const int* __restrict__ rowptr, int* __restrict__ fill,
                          int* __restrict__ col) {
    int e = blockIdx.x * blockDim.x + threadIdx.x;
    if (e < N_EDGES) {
        int d = dst[e];
        int pos = rowptr[d] + atomicAdd(&fill[d], 1);
        col[pos] = src[e];
    }
}

// ---------- dense kernels (persistent blocks, weights in LDS once) ----------

// layer 0 fused: hw = dis * ((x @ wn + bn) @ wc)
__global__ void __launch_bounds__(256)
k_embed_p(const float* __restrict__ x, const float* __restrict__ wn,
          const float* __restrict__ bn, const float* __restrict__ wc,
          const float* __restrict__ dis, float* __restrict__ hw) {
    __shared__ float wnl[F_NODE * HDIM];   // 8 KB
    __shared__ float wcl[HDIM * HDIM];     // 16 KB
    __shared__ float xs[4][4 * F_NODE];    // 2 KB
    __shared__ float ts[4][4 * HDIM];      // 4 KB
    int t = threadIdx.x;
    for (int i = t; i < F_NODE * HDIM; i += 256) wnl[i] = wn[i];
    for (int i = t; i < HDIM * HDIM; i += 256)   wcl[i] = wc[i];
    __syncthreads();
    int wid = t >> 6, lane = t & 63;
    float bnv = bn[lane];
    int gw = blockIdx.x * 4 + wid;
    const int nw = GB * 4;
    for (int c0 = gw * 4; c0 < N_NODES; c0 += nw * 4) {
        // stage 4 rows of x (128 contiguous floats)
        ((float2*)xs[wid])[lane] = ((const float2*)&x[(size_t)c0 * F_NODE])[lane];
        // stage 1: t = x @ wn + bn  (4 rows, wave-private, no barrier needed)
        #pragma unroll
        for (int r = 0; r < 4; ++r) {
            float acc = bnv;
            #pragma unroll
            for (int k = 0; k < F_NODE; k += 4) {
                float4 xb = *(const float4*)&xs[wid][r * F_NODE + k];
                acc += xb.x * wnl[(k + 0) * HDIM + lane]
                     + xb.y * wnl[(k + 1) * HDIM + lane]
                     + xb.z * wnl[(k + 2) * HDIM + lane]
                     + xb.w * wnl[(k + 3) * HDIM + lane];
            }
            ts[wid][r * HDIM + lane] = acc;
        }
        // stage 2: out = t @ wc, scaled by dis
        float a0 = 0.f, a1 = 0.f, a2 = 0.f, a3 = 0.f;
        #pragma unroll
        for (int k = 0; k < HDIM; k += 4) {
            float4 x0 = *(const float4*)&ts[wid][0 * HDIM + k];
            float4 x1 = *(const float4*)&ts[wid][1 * HDIM + k];
            float4 x2 = *(const float4*)&ts[wid][2 * HDIM + k];
            float4 x3 = *(const float4*)&ts[wid][3 * HDIM + k];
            float w0 = wcl[(k + 0) * HDIM + lane];
            float w1 = wcl[(k + 1) * HDIM + lane];
            float w2 = wcl[(k + 2) * HDIM + lane];
            float w3 = wcl[(k + 3) * HDIM + lane];
            a0 += x0.x * w0 + x0.y * w1 + x0.z * w2 + x0.w * w3;
            a1 += x1.x * w0 + x1.y * w1 + x1.z * w2 + x1.w * w3;
            a2 += x2.x * w0 + x2.y * w1 + x2.z * w2 + x2.w * w3;
            a3 += x3.x * w0 + x3.y * w1 + x3.z * w2 + x3.w * w3;
        }
        float4 dv = *(const float4*)&dis[c0];
        hw[(size_t)(c0 + 0) * HDIM + lane] = dv.x * a0;
        hw[(size_t)(c0 + 1) * HDIM + lane] = dv.y * a1;
        hw[(size_t)(c0 + 2) * HDIM + lane] = dv.z * a2;
        hw[(size_t)(c0 + 3) * HDIM + lane] = dv.w * a3;
    }
}

// hw = dis * (h @ w), persistent
__global__ void __launch_bounds__(256)
k_gemm_p(const float* __restrict__ h, const float* __restrict__ w,
         const float* __restrict__ dis, float* __restrict__ hw) {
    __shared__ float wl[HDIM * HDIM];      // 16 KB
    __shared__ float xs[4][4 * HDIM];      // 4 KB
    int t = threadIdx.x;
    for (int i = t; i < HDIM * HDIM; i += 256) wl[i] = w[i];
    __syncthreads();
    int wid = t >> 6, lane = t & 63;
    int gw = blockIdx.x * 4 + wid;
    const int nw = GB * 4;
    for (int c0 = gw * 4; c0 < N_NODES; c0 += nw * 4) {
        // stage 4 rows (256 contiguous floats): one float4 per lane
        ((float4*)xs[wid])[lane] = ((const float4*)&h[(size_t)c0 * HDIM])[lane];
        float a0 = 0.f, a1 = 0.f, a2 = 0.f, a3 = 0.f;
        #pragma unroll
        for (int k = 0; k < HDIM; k += 4) {
            float4 x0 = *(const float4*)&xs[wid][0 * HDIM + k];
            float4 x1 = *(const float4*)&xs[wid][1 * HDIM + k];
            float4 x2 = *(const float4*)&xs[wid][2 * HDIM + k];
            float4 x3 = *(const float4*)&xs[wid][3 * HDIM + k];
            float w0 = wl[(k + 0) * HDIM + lane];
            float w1 = wl[(k + 1) * HDIM + lane];
            float w2 = wl[(k + 2) * HDIM + lane];
            float w3 = wl[(k + 3) * HDIM + lane];
            a0 += x0.x * w0 + x0.y * w1 + x0.z * w2 + x0.w * w3;
            a1 += x1.x * w0 + x1.y * w1 + x1.z * w2 + x1.w * w3;
            a2 += x2.x * w0 + x2.y * w1 + x2.z * w2 + x2.w * w3;
            a3 += x3.x * w0 + x3.y * w1 + x3.z * w2 + x3.w * w3;
        }
        float4 dv = *(const float4*)&dis[c0];
        hw[(size_t)(c0 + 0) * HDIM + lane] = dv.x * a0;
        hw[(size_t)(c0 + 1) * HDIM + lane] = dv.y * a1;
        hw[(size_t)(c0 + 2) * HDIM + lane] = dv.z * a2;
        hw[(size_t)(c0 + 3) * HDIM + lane] = dv.w * a3;
    }
}

// ---------- pull aggregation ----------
// wave per node; 4 groups of 16 lanes, each group gathers one neighbor row
// as float4; cross-group reduction via shfl_xor at the end.
__global__ void __launch_bounds__(256)
k_pull(const float* __restrict__ hw, const int* __restrict__ rowptr,
       const int* __restrict__ col, const float* __restrict__ dis,
       const float* __restrict__ b, float* __restrict__ hout) {
    int wid = threadIdx.x >> 6, lane = threadIdx.x & 63;
    int v = blockIdx.x * 4 + wid;
    if (v >= N_NODES) return;
    int g = lane >> 4, f4 = lane & 15;
    int s0 = rowptr[v], s1 = rowptr[v + 1];
    float ax = 0.f, ay = 0.f, az = 0.f, aw = 0.f;
    for (int base = s0; base < s1; base += 64) {
        int m = s1 - base; if (m > 64) m = 64;
        int c = 0;
        if (lane < m) c = col[base + lane];
        for (int i = 0; i < m; i += 4) {
            int cs = __shfl(c, i + g);
            if (i + g < m) {
                float4 a = ((const float4*)&hw[(size_t)cs * HDIM])[f4];
                ax += a.x; ay += a.y; az += a.z; aw += a.w;
            }
        }
    }
    ax += __shfl_xor(ax, 16); ay += __shfl_xor(ay, 16);
    az += __shfl_xor(az, 16); aw += __shfl_xor(aw, 16);
    ax += __shfl_xor(ax, 32); ay += __shfl_xor(ay, 32);
    az += __shfl_xor(az, 32); aw += __shfl_xor(aw, 32);
    float4 self = ((const float4*)&hw[(size_t)v * HDIM])[f4];
    float4 bb = *(const float4*)&b[f4 * 4];
    float dv = dis[v];
    float4 o;
    o.x = fmaxf(bb.x + dv * (ax + self.x), 0.f);
    o.y = fmaxf(bb.y + dv * (ay + self.y), 0.f);
    o.z = fmaxf(bb.z + dv * (az + self.z), 0.f);
    o.w = fmaxf(bb.w + dv * (aw + self.w), 0.f);
    if (g == 0) ((float4*)&hout[(size_t)v * HDIM])[f4] = o;
}

// ---------- readout ----------

__global__ void k_mean(const float* __restrict__ h, float* __restrict__ partial) {
    __shared__ float lds[256];
    int t = threadIdx.x;
    int f = t & 63, g = t >> 6;
    float acc = 0.f;
    for (int v = blockIdx.x * 4 + g; v < N_NODES; v += gridDim.x * 4)
        acc += h[(size_t)v * HDIM + f];
    lds[t] = acc;
    __syncthreads();
    if (t < 64)
        partial[blockIdx.x * 64 + t] = lds[t] + lds[t + 64] + lds[t + 128] + lds[t + 192];
}

__global__ void k_final(const float* __restrict__ partial, int nparts,
                        const float* __restrict__ gfeat,
                        const float* __restrict__ wg, const float* __restrict__ bg,
                        const float* __restrict__ w1, const float* __restrict__ b1,
                        const float* __restrict__ w2, const float* __restrict__ b2,
                        float* __restrict__ out) {
    __shared__ float xc[2 * HDIM];
    __shared__ float hid[HDIM];
    int t = threadIdx.x;   // 64 threads
    float s = 0.f;
    for (int p = 0; p < nparts; ++p) s += partial[p * 64 + t];
    xc[t] = s / (float)N_NODES;                       // x_graph
    float gacc = bg[t];
    for (int k = 0; k < F_GLOB; ++k) gacc += gfeat[k] * wg[k * HDIM + t];
    xc[HDIM + t] = fmaxf(gacc, 0.f);                  // x_global
    __syncthreads();
    float hacc = b1[t];
    for (int k = 0; k < 2 * HDIM; ++k) hacc += xc[k] * w1[k * HDIM + t];
    hid[t] = fmaxf(hacc, 0.f);
    __syncthreads();
    float oacc = b2[t];
    for (int k = 0; k < HDIM; ++k) oacc += hid[k] * w2[k * OUTDIM + t];
    out[t] = oacc;
}

// ---------- launch ----------

extern "C" void kernel_launch(void* const* d_in, const int* in_sizes, int n_in,
                              void* d_out, int out_size, void* d_ws, size_t ws_size,
                              hipStream_t stream) {
    const float* x      = (const float*)d_in[0];
    const int*   eidx   = (const int*)d_in[1];
    const float* gfeat  = (const float*)d_in[2];
    const float* w_node = (const float*)d_in[3];
    const float* b_node = (const float*)d_in[4];
    const float* w_glob = (const float*)d_in[5];
    const float* b_glob = (const float*)d_in[6];
    const float* w_c[3] = {(const float*)d_in[7], (const float*)d_in[9], (const float*)d_in[11]};
    const float* b_c[3] = {(const float*)d_in[8], (const float*)d_in[10], (const float*)d_in[12]};
    const float* w_fc1  = (const float*)d_in[13];
    const float* b_fc1  = (const float*)d_in[14];
    const float* w_fc2  = (const float*)d_in[15];
    const float* b_fc2  = (const float*)d_in[16];
    float* out = (float*)d_out;

    const int* srcp = eidx;
    const int* dstp = eidx + N_EDGES;

    char* ws = (char*)d_ws;
    size_t off = 0;
    auto alloc = [&](size_t bytes) -> void* {
        void* p = ws + off;
        off = (off + bytes + 255) & ~(size_t)255;
        return p;
    };
    int*   cnt     = (int*)  alloc((size_t)N_NODES * 4);
    int*   rowptr  = (int*)  alloc((size_t)(N_NODES + 1) * 4);
    int*   fill    = (int*)  alloc((size_t)N_NODES * 4);
    int*   bsum    = (int*)  alloc(512 * 4);
    float* dis     = (float*)alloc((size_t)N_NODES * 4);
    int*   col     = (int*)  alloc((size_t)N_EDGES * 4);
    float* hbuf    = (float*)alloc((size_t)N_NODES * HDIM * 4);
    float* hwbuf   = (float*)alloc((size_t)N_NODES * HDIM * 4);
    float* partial = (float*)alloc(256 * 64 * 4);

    hipMemsetAsync(cnt,  0, (size_t)N_NODES * 4, stream);
    hipMemsetAsync(fill, 0, (size_t)N_NODES * 4, stream);

    int eb = (N_EDGES + 255) / 256;
    int nb = (N_NODES + 255) / 256;   // 391 (< 512, fits k_scan2)
    k_hist   <<<eb, 256, 0, stream>>>(dstp, cnt);
    k_scan1  <<<nb, 256, 0, stream>>>(cnt, rowptr, bsum, dis);
    k_scan2  <<<1, 512, 0, stream>>>(bsum, nb, rowptr);
    k_scan3  <<<nb, 256, 0, stream>>>(rowptr, bsum);
    k_scatter<<<eb, 256, 0, stream>>>(srcp, dstp, rowptr, fill, col);

    int pb = (N_NODES + 3) / 4;               // 25000, 1 node per wave

    // layer 0 (embed fused in)
    k_embed_p<<<GB, 256, 0, stream>>>(x, w_node, b_node, w_c[0], dis, hwbuf);
    k_pull   <<<pb, 256, 0, stream>>>(hwbuf, rowptr, col, dis, b_c[0], hbuf);
    // layers 1,2
    for (int l = 1; l < 3; ++l) {
        k_gemm_p<<<GB, 256, 0, stream>>>(hbuf, w_c[l], dis, hwbuf);
        k_pull  <<<pb, 256, 0, stream>>>(hwbuf, rowptr, col, dis, b_c[l], hbuf);
    }
    k_mean <<<256, 256, 0, stream>>>(hbuf, partial);
    k_final<<<1, 64, 0, stream>>>(partial, 256, gfeat, w_glob, b_glob,
                                  w_fc1, b_fc1, w_fc2, b_fc2, out);
}

// Round 4
// 551.404 us; speedup vs baseline: 1.5605x; 1.1531x over previous
//
#include <hip/hip_runtime.h>

#define N_NODES 100000
#define N_EDGES 1600000
#define F_NODE  32
#define F_GLOB  16
#define HDIM    64
#define OUTDIM  64
#define GB      2048   // persistent blocks for dense GEMMs
#define SBLK    128    // blocks per shard in scatter (grid = 8*SBLK)
#define SHARD_N 12500  // nodes per shard (100000/8)

typedef unsigned short u16;
typedef unsigned int   u32;

__device__ __forceinline__ u16 f2b(float f) {            // fp32 -> bf16 RNE
    u32 u = __float_as_uint(f);
    return (u16)((u + 0x7fffu + ((u >> 16) & 1u)) >> 16);
}
__device__ __forceinline__ float blo(u32 p) { return __uint_as_float(p << 16); }
__device__ __forceinline__ float bhi(u32 p) { return __uint_as_float(p & 0xffff0000u); }

// ---------- CSR build ----------

__global__ void k_hist(const int* __restrict__ dst, int* __restrict__ cnt) {
    int e = blockIdx.x * blockDim.x + threadIdx.x;
    if (e < N_EDGES) atomicAdd(&cnt[dst[e]], 1);
}

// scan1 + dis fused
__global__ void k_scan1(const int* __restrict__ cnt, int* __restrict__ rowptr,
                        int* __restrict__ bsum, float* __restrict__ dis) {
    __shared__ int lds[256];
    int t = threadIdx.x;
    int i = blockIdx.x * 256 + t;
    int v = (i < N_NODES) ? cnt[i] : 0;
    if (i < N_NODES) dis[i] = rsqrtf((float)(v + 1));   // +1 self-loop
    int x = v;
    lds[t] = x;
    __syncthreads();
    for (int ofs = 1; ofs < 256; ofs <<= 1) {
        int y = (t >= ofs) ? lds[t - ofs] : 0;
        __syncthreads();
        x += y;
        lds[t] = x;
        __syncthreads();
    }
    if (i < N_NODES) rowptr[i] = x - v;
    if (t == 255)    bsum[blockIdx.x] = x;
}

__global__ void k_scan2(int* __restrict__ bsum, int nb, int* __restrict__ rowptr) {
    __shared__ int lds[512];
    int t = threadIdx.x;
    int v = (t < nb) ? bsum[t] : 0;
    int x = v;
    lds[t] = x;
    __syncthreads();
    for (int ofs = 1; ofs < 512; ofs <<= 1) {
        int y = (t >= ofs) ? lds[t - ofs] : 0;
        __syncthreads();
        x += y;
        lds[t] = x;
        __syncthreads();
    }
    if (t < nb) bsum[t] = x - v;
    if (t == 0) rowptr[N_NODES] = N_EDGES;
}

__global__ void k_scan3(int* __restrict__ rowptr, const int* __restrict__ bsum) {
    int i = blockIdx.x * 256 + threadIdx.x;
    if (i < N_NODES) rowptr[i] += bsum[blockIdx.x];
}

// XCD-sharded scatter: shard = blockIdx&7 rides round-robin XCD dispatch;
// each shard group scans all edges (L2/L3-served) but writes only its
// 12500-node dst window -> col writes land in an ~800 KB L2-resident range.
__global__ void k_scatter(const int* __restrict__ src, const int* __restrict__ dst,
                          const int* __restrict__ rowptr, int* __restrict__ fill,
                          int* __restrict__ col) {
    int s = blockIdx.x & 7;
    int j = blockIdx.x >> 3;
    int lo = s * SHARD_N, hi = lo + SHARD_N;
    for (int e = j * 256 + threadIdx.x; e < N_EDGES; e += SBLK * 256) {
        int d = dst[e];
        if (d >= lo && d < hi) {
            int pos = rowptr[d] + atomicAdd(&fill[d], 1);
            col[pos] = src[e];
        }
    }
}

// ---------- dense kernels (persistent, weights in LDS once) ----------

// layer 0 fused: hw(bf16) = dis * ((x @ wn + bn) @ wc)
__global__ void __launch_bounds__(256)
k_embed_p(const float* __restrict__ x, const float* __restrict__ wn,
          const float* __restrict__ bn, const float* __restrict__ wc,
          const float* __restrict__ dis, u16* __restrict__ hw) {
    __shared__ float wnl[F_NODE * HDIM];
    __shared__ float wcl[HDIM * HDIM];
    __shared__ float xs[4][4 * F_NODE];
    __shared__ float ts[4][4 * HDIM];
    int t = threadIdx.x;
    for (int i = t; i < F_NODE * HDIM; i += 256) wnl[i] = wn[i];
    for (int i = t; i < HDIM * HDIM; i += 256)   wcl[i] = wc[i];
    __syncthreads();
    int wid = t >> 6, lane = t & 63;
    float bnv = bn[lane];
    int gw = blockIdx.x * 4 + wid;
    const int nw = GB * 4;
    for (int c0 = gw * 4; c0 < N_NODES; c0 += nw * 4) {
        ((float2*)xs[wid])[lane] = ((const float2*)&x[(size_t)c0 * F_NODE])[lane];
        #pragma unroll
        for (int r = 0; r < 4; ++r) {
            float acc = bnv;
            #pragma unroll
            for (int k = 0; k < F_NODE; k += 4) {
                float4 xb = *(const float4*)&xs[wid][r * F_NODE + k];
                acc += xb.x * wnl[(k + 0) * HDIM + lane]
                     + xb.y * wnl[(k + 1) * HDIM + lane]
                     + xb.z * wnl[(k + 2) * HDIM + lane]
                     + xb.w * wnl[(k + 3) * HDIM + lane];
            }
            ts[wid][r * HDIM + lane] = acc;
        }
        float a0 = 0.f, a1 = 0.f, a2 = 0.f, a3 = 0.f;
        #pragma unroll
        for (int k = 0; k < HDIM; k += 4) {
            float4 x0 = *(const float4*)&ts[wid][0 * HDIM + k];
            float4 x1 = *(const float4*)&ts[wid][1 * HDIM + k];
            float4 x2 = *(const float4*)&ts[wid][2 * HDIM + k];
            float4 x3 = *(const float4*)&ts[wid][3 * HDIM + k];
            float w0 = wcl[(k + 0) * HDIM + lane];
            float w1 = wcl[(k + 1) * HDIM + lane];
            float w2 = wcl[(k + 2) * HDIM + lane];
            float w3 = wcl[(k + 3) * HDIM + lane];
            a0 += x0.x * w0 + x0.y * w1 + x0.z * w2 + x0.w * w3;
            a1 += x1.x * w0 + x1.y * w1 + x1.z * w2 + x1.w * w3;
            a2 += x2.x * w0 + x2.y * w1 + x2.z * w2 + x2.w * w3;
            a3 += x3.x * w0 + x3.y * w1 + x3.z * w2 + x3.w * w3;
        }
        float4 dv = *(const float4*)&dis[c0];
        hw[(size_t)(c0 + 0) * HDIM + lane] = f2b(dv.x * a0);
        hw[(size_t)(c0 + 1) * HDIM + lane] = f2b(dv.y * a1);
        hw[(size_t)(c0 + 2) * HDIM + lane] = f2b(dv.z * a2);
        hw[(size_t)(c0 + 3) * HDIM + lane] = f2b(dv.w * a3);
    }
}

// hw(bf16) = dis * (h(bf16) @ w), persistent
__global__ void __launch_bounds__(256)
k_gemm_p(const u16* __restrict__ h, const float* __restrict__ w,
         const float* __restrict__ dis, u16* __restrict__ hw) {
    __shared__ float wl[HDIM * HDIM];
    __shared__ float xs[4][4 * HDIM];
    int t = threadIdx.x;
    for (int i = t; i < HDIM * HDIM; i += 256) wl[i] = w[i];
    __syncthreads();
    int wid = t >> 6, lane = t & 63;
    int gw = blockIdx.x * 4 + wid;
    const int nw = GB * 4;
    for (int c0 = gw * 4; c0 < N_NODES; c0 += nw * 4) {
        uint2 rv = ((const uint2*)(h + (size_t)c0 * HDIM))[lane];  // 4 bf16
        float4 xf;
        xf.x = blo(rv.x); xf.y = bhi(rv.x);
        xf.z = blo(rv.y); xf.w = bhi(rv.y);
        ((float4*)xs[wid])[lane] = xf;
        float a0 = 0.f, a1 = 0.f, a2 = 0.f, a3 = 0.f;
        #pragma unroll
        for (int k = 0; k < HDIM; k += 4) {
            float4 x0 = *(const float4*)&xs[wid][0 * HDIM + k];
            float4 x1 = *(const float4*)&xs[wid][1 * HDIM + k];
            float4 x2 = *(const float4*)&xs[wid][2 * HDIM + k];
            float4 x3 = *(const float4*)&xs[wid][3 * HDIM + k];
            float w0 = wl[(k + 0) * HDIM + lane];
            float w1 = wl[(k + 1) * HDIM + lane];
            float w2 = wl[(k + 2) * HDIM + lane];
            float w3 = wl[(k + 3) * HDIM + lane];
            a0 += x0.x * w0 + x0.y * w1 + x0.z * w2 + x0.w * w3;
            a1 += x1.x * w0 + x1.y * w1 + x1.z * w2 + x1.w * w3;
            a2 += x2.x * w0 + x2.y * w1 + x2.z * w2 + x2.w * w3;
            a3 += x3.x * w0 + x3.y * w1 + x3.z * w2 + x3.w * w3;
        }
        float4 dv = *(const float4*)&dis[c0];
        hw[(size_t)(c0 + 0) * HDIM + lane] = f2b(dv.x * a0);
        hw[(size_t)(c0 + 1) * HDIM + lane] = f2b(dv.y * a1);
        hw[(size_t)(c0 + 2) * HDIM + lane] = f2b(dv.z * a2);
        hw[(size_t)(c0 + 3) * HDIM + lane] = f2b(dv.w * a3);
    }
}

// ---------- pull aggregation (bf16 rows = 128B; 8 lanes/row, 8 edges/iter) ----------

__global__ void __launch_bounds__(256)
k_pull(const u16* __restrict__ hw, const int* __restrict__ rowptr,
       const int* __restrict__ col, const float* __restrict__ dis,
       const float* __restrict__ b, u16* __restrict__ hout) {
    int wid = threadIdx.x >> 6, lane = threadIdx.x & 63;
    int v = blockIdx.x * 4 + wid;
    if (v >= N_NODES) return;
    int g = lane >> 3, sub = lane & 7;      // g: edge slot, sub: 8-feature chunk
    float acc[8] = {0.f, 0.f, 0.f, 0.f, 0.f, 0.f, 0.f, 0.f};
    int s0 = rowptr[v], s1 = rowptr[v + 1];
    for (int base = s0; base < s1; base += 64) {
        int m = s1 - base; if (m > 64) m = 64;
        int c = 0;
        if (lane < m) c = col[base + lane];
        for (int i = 0; i < m; i += 8) {
            int cs = __shfl(c, i + g);
            if (i + g < m) {
                uint4 a = *(const uint4*)(hw + (size_t)cs * HDIM + sub * 8);
                acc[0] += blo(a.x); acc[1] += bhi(a.x);
                acc[2] += blo(a.y); acc[3] += bhi(a.y);
                acc[4] += blo(a.z); acc[5] += bhi(a.z);
                acc[6] += blo(a.w); acc[7] += bhi(a.w);
            }
        }
    }
    #pragma unroll
    for (int k = 0; k < 8; ++k) {
        acc[k] += __shfl_xor(acc[k], 8);
        acc[k] += __shfl_xor(acc[k], 16);
        acc[k] += __shfl_xor(acc[k], 32);
    }
    uint4 sv = *(const uint4*)(hw + (size_t)v * HDIM + sub * 8);   // self row
    float se[8];
    se[0] = blo(sv.x); se[1] = bhi(sv.x); se[2] = blo(sv.y); se[3] = bhi(sv.y);
    se[4] = blo(sv.z); se[5] = bhi(sv.z); se[6] = blo(sv.w); se[7] = bhi(sv.w);
    float4 b0 = *(const float4*)&b[sub * 8];
    float4 b1 = *(const float4*)&b[sub * 8 + 4];
    float bb[8] = {b0.x, b0.y, b0.z, b0.w, b1.x, b1.y, b1.z, b1.w};
    float dv = dis[v];
    u32 r[8];
    #pragma unroll
    for (int k = 0; k < 8; ++k) {
        float val = fmaxf(bb[k] + dv * (acc[k] + se[k]), 0.f);
        u32 u = __float_as_uint(val);
        r[k] = (u + 0x7fffu + ((u >> 16) & 1u)) >> 16;
    }
    uint4 pk;
    pk.x = r[0] | (r[1] << 16); pk.y = r[2] | (r[3] << 16);
    pk.z = r[4] | (r[5] << 16); pk.w = r[6] | (r[7] << 16);
    if (g == 0) *(uint4*)(hout + (size_t)v * HDIM + sub * 8) = pk;
}

// ---------- readout ----------

__global__ void k_mean(const u16* __restrict__ h, float* __restrict__ partial) {
    __shared__ float lds[256];
    int t = threadIdx.x;
    int f = t & 63, g = t >> 6;
    float acc = 0.f;
    for (int v = blockIdx.x * 4 + g; v < N_NODES; v += gridDim.x * 4)
        acc += __uint_as_float((u32)h[(size_t)v * HDIM + f] << 16);
    lds[t] = acc;
    __syncthreads();
    if (t < 64)
        partial[blockIdx.x * 64 + t] = lds[t] + lds[t + 64] + lds[t + 128] + lds[t + 192];
}

__global__ void k_final(const float* __restrict__ partial, int nparts,
                        const float* __restrict__ gfeat,
                        const float* __restrict__ wg, const float* __restrict__ bg,
                        const float* __restrict__ w1, const float* __restrict__ b1,
                        const float* __restrict__ w2, const float* __restrict__ b2,
                        float* __restrict__ out) {
    __shared__ float xc[2 * HDIM];
    __shared__ float hid[HDIM];
    int t = threadIdx.x;   // 64 threads
    float s = 0.f;
    for (int p = 0; p < nparts; ++p) s += partial[p * 64 + t];
    xc[t] = s / (float)N_NODES;
    float gacc = bg[t];
    for (int k = 0; k < F_GLOB; ++k) gacc += gfeat[k] * wg[k * HDIM + t];
    xc[HDIM + t] = fmaxf(gacc, 0.f);
    __syncthreads();
    float hacc = b1[t];
    for (int k = 0; k < 2 * HDIM; ++k) hacc += xc[k] * w1[k * HDIM + t];
    hid[t] = fmaxf(hacc, 0.f);
    __syncthreads();
    float oacc = b2[t];
    for (int k = 0; k < HDIM; ++k) oacc += hid[k] * w2[k * OUTDIM + t];
    out[t] = oacc;
}

// ---------- launch ----------

extern "C" void kernel_launch(void* const* d_in, const int* in_sizes, int n_in,
                              void* d_out, int out_size, void* d_ws, size_t ws_size,
                              hipStream_t stream) {
    const float* x      = (const float*)d_in[0];
    const int*   eidx   = (const int*)d_in[1];
    const float* gfeat  = (const float*)d_in[2];
    const float* w_node = (const float*)d_in[3];
    const float* b_node = (const float*)d_in[4];
    const float* w_glob = (const float*)d_in[5];
    const float* b_glob = (const float*)d_in[6];
    const float* w_c[3] = {(const float*)d_in[7], (const float*)d_in[9], (const float*)d_in[11]};
    const float* b_c[3] = {(const float*)d_in[8], (const float*)d_in[10], (const float*)d_in[12]};
    const float* w_fc1  = (const float*)d_in[13];
    const float* b_fc1  = (const float*)d_in[14];
    const float* w_fc2  = (const float*)d_in[15];
    const float* b_fc2  = (const float*)d_in[16];
    float* out = (float*)d_out;

    const int* srcp = eidx;
    const int* dstp = eidx + N_EDGES;

    char* ws = (char*)d_ws;
    size_t off = 0;
    auto alloc = [&](size_t bytes) -> void* {
        void* p = ws + off;
        off = (off + bytes + 255) & ~(size_t)255;
        return p;
    };
    int*   cnt     = (int*)  alloc((size_t)N_NODES * 4);
    int*   rowptr  = (int*)  alloc((size_t)(N_NODES + 1) * 4);
    int*   fill    = (int*)  alloc((size_t)N_NODES * 4);
    int*   bsum    = (int*)  alloc(512 * 4);
    float* dis     = (float*)alloc((size_t)N_NODES * 4);
    int*   col     = (int*)  alloc((size_t)N_EDGES * 4);
    u16*   hbuf    = (u16*)  alloc((size_t)N_NODES * HDIM * 2);
    u16*   hwbuf   = (u16*)  alloc((size_t)N_NODES * HDIM * 2);
    float* partial = (float*)alloc(256 * 64 * 4);

    hipMemsetAsync(cnt,  0, (size_t)N_NODES * 4, stream);
    hipMemsetAsync(fill, 0, (size_t)N_NODES * 4, stream);

    int eb = (N_EDGES + 255) / 256;
    int nb = (N_NODES + 255) / 256;   // 391 (< 512, fits k_scan2)
    k_hist   <<<eb, 256, 0, stream>>>(dstp, cnt);
    k_scan1  <<<nb, 256, 0, stream>>>(cnt, rowptr, bsum, dis);
    k_scan2  <<<1, 512, 0, stream>>>(bsum, nb, rowptr);
    k_scan3  <<<nb, 256, 0, stream>>>(rowptr, bsum);
    k_scatter<<<8 * SBLK, 256, 0, stream>>>(srcp, dstp, rowptr, fill, col);

    int pb = (N_NODES + 3) / 4;       // 25000 blocks, 1 node per wave

    k_embed_p<<<GB, 256, 0, stream>>>(x, w_node, b_node, w_c[0], dis, hwbuf);
    k_pull   <<<pb, 256, 0, stream>>>(hwbuf, rowptr, col, dis, b_c[0], hbuf);
    for (int l = 1; l < 3; ++l) {
        k_gemm_p<<<GB, 256, 0, stream>>>(hbuf, w_c[l], dis, hwbuf);
        k_pull  <<<pb, 256, 0, stream>>>(hwbuf, rowptr, col, dis, b_c[l], hbuf);
    }
    k_mean <<<256, 256, 0, stream>>>(hbuf, partial);
    k_final<<<1, 64, 0, stream>>>(partial, 256, gfeat, w_glob, b_glob,
                                  w_fc1, b_fc1, w_fc2, b_fc2, out);
}